// Round 14
// baseline (263.807 us; speedup 1.0000x reference)
//
#include <hip/hip_runtime.h>
#include <hip/hip_bf16.h>
#include <cstdint>

#define DI __device__ __forceinline__

typedef float f32x4 __attribute__((ext_vector_type(4)));
typedef short bf16x8 __attribute__((ext_vector_type(8)));
typedef unsigned short u16x4 __attribute__((ext_vector_type(4)));

constexpr int B_ = 8, C_ = 256, HH = 48, WW = 48, N_ = 2304, CR = 32;
constexpr float QK_SCALE = 0.17677669529663687f;   // 32^-0.5
constexpr float BN_SC = 0.99999500003749968f;      // 1/sqrt(1+1e-5)

// ---------------- workspace layout (bytes) ----------------
constexpr size_t QK_SZ   = (size_t)B_*N_*CR*2;         // bf16 [B][N][32]
constexpr size_t V_SZ    = (size_t)B_*C_*N_*2;         // bf16 [B][C][N]
constexpr size_t OFF_RQT = 0;
constexpr size_t OFF_RKT = OFF_RQT + QK_SZ;
constexpr size_t OFF_DQT = OFF_RKT + QK_SZ;
constexpr size_t OFF_DKT = OFF_DQT + QK_SZ;
constexpr size_t OFF_RV  = OFF_DKT + QK_SZ;            // scaled in-place by phase_a
constexpr size_t OFF_DV  = OFF_RV + V_SZ;
constexpr size_t OFF_ATT = OFF_DV + V_SZ;              // bf16 [a][b][c][m]  18.9 MB (late)
constexpr size_t ATT_SZ  = 2ull*B_*C_*N_*2;
constexpr size_t OFF_PCS = OFF_ATT;                    // f32 [2][8][36][256] (early, dead before att)
constexpr size_t OFF_PCM = OFF_ATT + 2ull*8*36*256*4;
constexpr size_t OFF_SCONV = OFF_ATT + ATT_SZ;         // f32 [2][B][2][N]
constexpr size_t SCONV_SZ  = 2ull*B_*2*N_*4;
constexpr size_t OFF_SA    = OFF_SCONV + SCONV_SZ;     // f32 [2][B][N]
constexpr size_t SA_SZ     = 2ull*B_*N_*4;
constexpr size_t OFF_CA    = OFF_SA + SA_SZ;           // f32 [2][B][C]
constexpr size_t CST_SZ    = 2ull*B_*C_*4;
constexpr size_t OFF_WPROJ = OFF_CA + CST_SZ;          // bf16 [2][320][256]
constexpr size_t WPROJ_SZ  = 2ull*320*256*2;
constexpr size_t OFF_WGATE = OFF_WPROJ + WPROJ_SZ;     // bf16 [256][512]
constexpr size_t WS_NEEDED = OFF_WGATE + 256ull*512*2;

DI float bf2f(unsigned short u){ union{unsigned int i; float f;} v; v.i = ((unsigned int)u)<<16; return v.f; }
DI unsigned short f2bf(float f){ union{float f; unsigned int i;} v; v.f=f; unsigned int r = v.i + 0x7fffu + ((v.i>>16)&1u); return (unsigned short)(r>>16); }
DI float sigm(float x){ return 1.0f/(1.0f+__expf(-x)); }
DI u16x4 pk4(float p0, float p1, float p2, float p3){
  union { __hip_bfloat162 h[2]; u16x4 v; } u;
  u.h[0] = __float22bfloat162_rn(make_float2(p0, p1));
  u.h[1] = __float22bfloat162_rn(make_float2(p2, p3));
  return u.v;
}

// ---------------- 1. cast/stack weights to bf16 ----------------
__global__ void k_prep_w(const float* rq_w, const float* rk_w, const float* rv_w,
                         const float* dq_w, const float* dk_w, const float* dv_w,
                         const float* gate_w, unsigned short* wproj, unsigned short* wgate){
  int i = blockIdx.x*256 + threadIdx.x;
  if (i < 163840){
    int mod = i / 81920, r = (i >> 8) % 320, c = i & 255;
    const float* q = mod ? dq_w : rq_w;
    const float* k = mod ? dk_w : rk_w;
    const float* v = mod ? dv_w : rv_w;
    float val = (r < 32) ? q[r*256+c] : (r < 64 ? k[(r-32)*256+c] : v[(r-64)*256+c]);
    wproj[i] = f2bf(val);
  } else {
    int j = i - 163840;
    if (j < 131072) wgate[j] = f2bf(gate_w[j]);
  }
}

// ---------------- 2. fused: X one-pass -> reductions + q/k/v projection (XCD-pinned b) ----------------
__global__ __launch_bounds__(256, 2) void k_stage(
                       const float* rgb, const float* chm, const unsigned short* wproj,
                       const float* rq_b, const float* rk_b, const float* rv_b,
                       const float* dq_b, const float* dk_b, const float* dv_b,
                       unsigned short* wsu, float* sconv, float* pcs, float* pcm){
  int mod = blockIdx.y;
  int x = blockIdx.x;
  int b = x & 7, nt = x >> 3;          // XCD pin: XCD k produces b=k (288 = 8*36 exact)
  int pix0 = nt*64;
  const float* X = (mod ? chm : rgb) + (size_t)b*C_*N_ + pix0;
  __shared__ unsigned short xs[256*68];   // [ch 256][pix 64] bf16, pitch 68
  __shared__ float ls[4][64], lm[4][64];
  int t = threadIdx.x;
  {
    int srow = t >> 4;           // 0..15
    int scol = (t & 15) * 4;     // 0..60
    #pragma unroll
    for (int rr = 0; rr < 16; ++rr){
      int row = rr*16 + srow;
      float4 v = *(const float4*)(X + (size_t)row*N_ + scol);
      u16x4 h = { f2bf(v.x), f2bf(v.y), f2bf(v.z), f2bf(v.w) };
      *(u16x4*)(xs + row*68 + scol) = h;
    }
  }
  __syncthreads();
  {
    int p = t & 63, cg = t >> 6;
    float s = 0.f, mx = -INFINITY;
    for (int cc = 0; cc < 64; ++cc){
      float v = bf2f(xs[(cg*64+cc)*68 + p]);
      s += v; mx = fmaxf(mx, v);
    }
    ls[cg][p] = s; lm[cg][p] = mx;
  }
  {
    float cs = 0.f, cm = -INFINITY;
    for (int p = 0; p < 64; ++p){
      float v = bf2f(xs[t*68 + p]);
      cs += v; cm = fmaxf(cm, v);
    }
    pcs[((size_t)(mod*8+b)*36 + nt)*256 + t] = cs;
    pcm[((size_t)(mod*8+b)*36 + nt)*256 + t] = cm;
  }
  __syncthreads();
  if (t < 64){
    int p = t;
    float s = ls[0][p]+ls[1][p]+ls[2][p]+ls[3][p];
    float mx = fmaxf(fmaxf(lm[0][p],lm[1][p]), fmaxf(lm[2][p],lm[3][p]));
    sconv[((size_t)(mod*B_+b)*2 + 0)*N_ + pix0+p] = s*(1.f/256.f);
    sconv[((size_t)(mod*B_+b)*2 + 1)*N_ + pix0+p] = mx;
  }
  const unsigned short* Wm = wproj + (size_t)mod*320*256;
  int lane = t & 63, w = t >> 6;
  int l15 = lane & 15, g = lane >> 4;
  f32x4 acc[5][4];
  #pragma unroll
  for (int i = 0; i < 5; ++i)
    #pragma unroll
    for (int j = 0; j < 4; ++j) acc[i][j] = 0.f;
  for (int k0 = 0; k0 < 256; k0 += 32){
    bf16x8 af[5];
    #pragma unroll
    for (int cf = 0; cf < 5; ++cf)
      af[cf] = *(const bf16x8*)(Wm + (size_t)(w*80 + cf*16 + l15)*256 + k0 + g*8);
    bf16x8 bx[4];
    #pragma unroll
    for (int mf = 0; mf < 4; ++mf)
      #pragma unroll
      for (int j = 0; j < 8; ++j)
        bx[mf][j] = (short)xs[(k0 + g*8 + j)*68 + mf*16 + l15];
    #pragma unroll
    for (int cf = 0; cf < 5; ++cf)
      #pragma unroll
      for (int mf = 0; mf < 4; ++mf)
        acc[cf][mf] = __builtin_amdgcn_mfma_f32_16x16x32_bf16(af[cf], bx[mf], acc[cf][mf], 0, 0, 0);
  }
  const float* qb = mod ? dq_b : rq_b;
  const float* kb = mod ? dk_b : rk_b;
  const float* vb = mod ? dv_b : rv_b;
  unsigned short* qT = wsu + (mod ? OFF_DQT : OFF_RQT)/2;
  unsigned short* kT = wsu + (mod ? OFF_DKT : OFF_RKT)/2;
  unsigned short* vB = wsu + (mod ? OFF_DV  : OFF_RV )/2;
  #pragma unroll
  for (int cf = 0; cf < 5; ++cf){
    int base = w*80 + cf*16;
    #pragma unroll
    for (int mf = 0; mf < 4; ++mf){
      int col = pix0 + mf*16 + l15;
      if (base < 32){
        int o4 = base + g*4;
        u16x4 pk = { f2bf(acc[cf][mf][0] + qb[o4]),   f2bf(acc[cf][mf][1] + qb[o4+1]),
                     f2bf(acc[cf][mf][2] + qb[o4+2]), f2bf(acc[cf][mf][3] + qb[o4+3]) };
        *(u16x4*)(qT + (size_t)(b*N_ + col)*32 + o4) = pk;
      } else if (base < 64){
        int o4 = base - 32 + g*4;
        u16x4 pk = { f2bf(acc[cf][mf][0] + kb[o4]),   f2bf(acc[cf][mf][1] + kb[o4+1]),
                     f2bf(acc[cf][mf][2] + kb[o4+2]), f2bf(acc[cf][mf][3] + kb[o4+3]) };
        *(u16x4*)(kT + (size_t)(b*N_ + col)*32 + o4) = pk;
      } else {
        #pragma unroll
        for (int r = 0; r < 4; ++r){
          int o = base - 64 + g*4 + r;
          vB[((size_t)b*C_ + o)*N_ + col] = f2bf(acc[cf][mf][r] + vb[o]);
        }
      }
    }
  }
}

// ---------------- 3. merged 7x7 conv + channel-attn MLP ----------------
__global__ void k_sa_ca(const float* sconv, const float* rgb_sa_w, const float* rgb_sa_b,
                        const float* chm_sa_w, const float* chm_sa_b, float* sa,
                        const float* pcs, const float* pcm,
                        const float* rw1, const float* rb1, const float* rw2, const float* rb2,
                        const float* cw1, const float* cb1, const float* cw2, const float* cb2,
                        float* ca){
  int x = blockIdx.x;
  if (x < 144){
    int mod = x / 72;
    int idx = (x % 72)*256 + threadIdx.x;
    int b = idx / N_, pix = idx % N_;
    int y = pix / WW, xx0 = pix % WW;
    const float* w7 = mod ? chm_sa_w : rgb_sa_w;
    float acc = (mod ? chm_sa_b : rgb_sa_b)[0];
    const float* sin0 = sconv + (size_t)(mod*B_+b)*2*N_;
    #pragma unroll
    for (int ic = 0; ic < 2; ++ic)
      for (int ky = 0; ky < 7; ++ky){
        int yy = y + ky - 3; if (yy < 0 || yy >= HH) continue;
        for (int kx = 0; kx < 7; ++kx){
          int xx = xx0 + kx - 3; if (xx < 0 || xx >= WW) continue;
          acc += w7[(ic*7+ky)*7+kx] * sin0[ic*N_ + yy*WW + xx];
        }
      }
    sa[(mod*B_+b)*N_ + pix] = sigm(acc);
  } else {
    int y = x - 144;
    int mod = y >> 3, b = y & 7;
    const float* w1 = mod ? cw1 : rw1;  const float* b1 = mod ? cb1 : rb1;
    const float* w2 = mod ? cw2 : rw2;  const float* b2 = mod ? cb2 : rb2;
    __shared__ float va[256], vm[256], h1a[16], h1m[16];
    int t = threadIdx.x;
    float s = 0.f, mx = -INFINITY;
    for (int nt = 0; nt < 36; ++nt){
      s += pcs[((size_t)(mod*8+b)*36 + nt)*256 + t];
      mx = fmaxf(mx, pcm[((size_t)(mod*8+b)*36 + nt)*256 + t]);
    }
    va[t] = s*(1.f/(float)N_);
    vm[t] = mx;
    __syncthreads();
    if (t < 32){
      int j = t & 15;
      const float* v = (t >= 16) ? vm : va;
      float ss = b1[j];
      for (int c = 0; c < 256; ++c) ss += w1[j*256+c]*v[c];
      float* hp = (t >= 16) ? h1m : h1a;
      hp[j] = fmaxf(ss, 0.f);
    }
    __syncthreads();
    float fa = b2[t], fm = b2[t];
    #pragma unroll
    for (int j = 0; j < 16; ++j){ fa += w2[t*16+j]*h1a[j]; fm += w2[t*16+j]*h1m[j]; }
    ca[(mod*B_+b)*C_ + t] = sigm(fa + fm);
  }
}

// ---------------- 4. softmax denominators + in-place V scaling (XCD-pinned; warms L2) ----------------
__global__ void k_phase_a(unsigned short* wsu){
  int orig = blockIdx.x;
  int b = orig & 7;
  int logical = orig >> 3;          // 0..71
  int a = logical / 36;
  int nb0 = (logical % 36)*64;
  int lane = threadIdx.x & 63, w = threadIdx.x >> 6;
  int l15 = lane & 15, g = lane >> 4;
  int n0 = nb0 + w*16;
  const unsigned short* Q = wsu + (a ? OFF_DQT : OFF_RQT)/2;
  const unsigned short* K = wsu + (a ? OFF_RKT : OFF_DKT)/2;
  bf16x8 af = *(const bf16x8*)(Q + (size_t)(b*N_ + n0 + l15)*32 + g*8);
  float lrun[4] = {0.f,0.f,0.f,0.f};
  for (int m0 = 0; m0 < N_; m0 += 64){
    f32x4 d[4];
    #pragma unroll
    for (int s = 0; s < 4; ++s){
      bf16x8 bk = *(const bf16x8*)(K + (size_t)(b*N_ + m0 + s*16 + l15)*32 + g*8);
      f32x4 z = 0.f;
      d[s] = __builtin_amdgcn_mfma_f32_16x16x32_bf16(af, bk, z, 0, 0, 0);
    }
    #pragma unroll
    for (int r = 0; r < 4; ++r)
      lrun[r] += (__expf(d[0][r]*QK_SCALE)+__expf(d[1][r]*QK_SCALE))
               + (__expf(d[2][r]*QK_SCALE)+__expf(d[3][r]*QK_SCALE));
  }
  #pragma unroll
  for (int r = 0; r < 4; ++r)
    #pragma unroll
    for (int msk = 1; msk < 16; msk <<= 1) lrun[r] += __shfl_xor(lrun[r], msk);
  __shared__ float lsv[64];
  if (l15 == 0){
    #pragma unroll
    for (int r = 0; r < 4; ++r) lsv[w*16 + g*4 + r] = 1.0f / lrun[r];
  }
  __syncthreads();
  unsigned short* V = wsu + (a ? OFF_DV : OFF_RV)/2 + ((size_t)b*C_ + threadIdx.x)*N_ + nb0;
  #pragma unroll
  for (int j8 = 0; j8 < 8; ++j8){
    bf16x8 vv = *(const bf16x8*)(V + j8*8);
    bf16x8 ov;
    #pragma unroll
    for (int e = 0; e < 8; ++e)
      ov[e] = (short)f2bf(bf2f((unsigned short)vv[e]) * lsv[j8*8 + e]);
    *(bf16x8*)(V + j8*8) = ov;
  }
}

// ---------------- 5. PV: m64 full-C, BN=128/interval, fixed swizzle + V pipeline ----------------
__global__ __launch_bounds__(256, 3) void k_pv5(
                          const unsigned short* wsu, unsigned short* att){
  int orig = blockIdx.x;
  int logical = (orig & 7)*72 + (orig >> 3);
  int pair = logical / 36, mblk = logical % 36;
  int a = pair >> 3, b = pair & 7;
  int m0 = mblk*64;
  int lane = threadIdx.x & 63, w = threadIdx.x >> 6;
  int l15 = lane & 15, g = lane >> 4;
  int qm  = (w & 1)*32;     // this wave's P m-offset
  int qnn = (w >> 1)*64;    // this wave's P n-offset (within 128)
  const unsigned short* Q = wsu + (a ? OFF_DQT : OFF_RQT)/2;
  const unsigned short* K = wsu + (a ? OFF_RKT : OFF_DKT)/2;
  const unsigned short* V = wsu + (a ? OFF_DV  : OFF_RV )/2;   // pre-scaled by 1/D
  __shared__ __align__(16) unsigned char plds[2][64*256];  // [buf][m 64][256B], xor swizzle

  bf16x8 kb[2];
  #pragma unroll
  for (int s = 0; s < 2; ++s)
    kb[s] = *(const bf16x8*)(K + (size_t)(b*N_ + m0 + qm + s*16 + l15)*32 + g*8);

  f32x4 acc[4][4];
  #pragma unroll
  for (int i = 0; i < 4; ++i)
    #pragma unroll
    for (int j = 0; j < 4; ++j) acc[i][j] = 0.f;

  auto computePh = [&](int n0base, int buf, int half){
    #pragma unroll
    for (int fi = 0; fi < 2; ++fi){
      int fr = half*2 + fi;
      int nb = n0base + qnn + fr*16;
      bf16x8 qa = *(const bf16x8*)(Q + (size_t)(b*N_ + nb + l15)*32 + g*8);
      #pragma unroll
      for (int fm = 0; fm < 2; ++fm){
        f32x4 z = 0.f;
        f32x4 d = __builtin_amdgcn_mfma_f32_16x16x32_bf16(qa, kb[fm], z, 0, 0, 0);
        int ml = qm + fm*16 + l15;
        int nl = qnn + fr*16 + g*4;
        u16x4 pk = pk4(__expf(d[0]*QK_SCALE), __expf(d[1]*QK_SCALE),
                       __expf(d[2]*QK_SCALE), __expf(d[3]*QK_SCALE));
        *(u16x4*)(plds[buf] + ml*256 + ((nl*2) ^ ((ml&15)<<4))) = pk;
      }
    }
  };

  const unsigned short* Vb = V + ((size_t)b*C_ + w*64 + l15)*N_;   // + cf*16*N_ + n

  computePh(0, 0, 0);
  computePh(0, 0, 1);
  __syncthreads();
  for (int t = 0; t < 18; ++t){
    int n0 = t*128;
    const unsigned char* pbuf = plds[t & 1];
    bf16x8 av[2][4];
    #pragma unroll
    for (int ss = 0; ss < 2; ++ss)
      #pragma unroll
      for (int cf = 0; cf < 4; ++cf)
        av[ss][cf] = *(const bf16x8*)(Vb + (size_t)cf*16*N_ + n0 + ss*32 + g*8);
    #pragma unroll
    for (int s = 0; s < 4; ++s){
      bf16x8 pb[4];
      #pragma unroll
      for (int mf = 0; mf < 4; ++mf){
        int ml = mf*16 + l15;
        pb[mf] = *(const bf16x8*)(pbuf + ml*256 + ((s*64 + g*16) ^ ((ml&15)<<4)));
      }
      if (t < 17 && s < 2) computePh(n0 + 128, (t+1)&1, s);
      __builtin_amdgcn_s_setprio(1);
      #pragma unroll
      for (int cf = 0; cf < 4; ++cf)
        #pragma unroll
        for (int mf = 0; mf < 4; ++mf)
          acc[cf][mf] = __builtin_amdgcn_mfma_f32_16x16x32_bf16(av[s&1][cf], pb[mf], acc[cf][mf], 0, 0, 0);
      __builtin_amdgcn_s_setprio(0);
      if (s < 2){
        #pragma unroll
        for (int cf = 0; cf < 4; ++cf)
          av[s][cf] = *(const bf16x8*)(Vb + (size_t)cf*16*N_ + n0 + (s+2)*32 + g*8);
      }
    }
    __syncthreads();
  }
  unsigned short* ap = att + (((size_t)a*8 + b)*256)*N_;
  #pragma unroll
  for (int cf = 0; cf < 4; ++cf)
    #pragma unroll
    for (int mf = 0; mf < 4; ++mf)
      #pragma unroll
      for (int r = 0; r < 4; ++r){
        int c = w*64 + cf*16 + g*4 + r;
        int m = m0 + mf*16 + l15;
        ap[(size_t)c*N_ + m] = f2bf(acc[cf][mf][r]);
      }
}

// ---------------- 6. gate GEMM + fuse + MLP + final combine (XCD-pinned b) ----------------
__global__ __launch_bounds__(256, 2) void k_gatemlp(
                           const unsigned short* att, const unsigned short* wgate,
                           const float* gate_b,
                           const float* w1, const float* g1, const float* b1,
                           const float* w2, const float* g2, const float* b2,
                           const float* rgb, const float* chm, const float* sa, const float* ca,
                           float* out){
  int orig = blockIdx.x;
  int b = orig & 7, m0 = (orig >> 3)*32;   // XCD pin: att[.][b] stays in XCD(b) L2
  int lane = threadIdx.x & 63, w = threadIdx.x >> 6;
  int l15 = lane & 15, g = lane >> 4;
  __shared__ unsigned short ats[32][520];   // [m local][k = a*256+c]
  __shared__ unsigned short fvs[256][34];   // [c][m local] bf16
  __shared__ float hs[24][33];
  __shared__ float swm[32], ssr[32], ssc[32];
  int row8 = threadIdx.x >> 3;      // 0..31
  int mq = (threadIdx.x & 7)*4;     // m offset
  for (int rb = 0; rb < 16; ++rb){
    int k = rb*32 + row8;           // 0..511
    int aa = k >> 8, c = k & 255;
    size_t base = (((size_t)aa*8 + b)*256 + c)*N_ + m0 + mq;
    u16x4 p0 = *(const u16x4*)(att + base);
    #pragma unroll
    for (int j = 0; j < 4; ++j) ats[mq + j][k] = p0[j];
  }
  __syncthreads();
  f32x4 acc[4][2];
  #pragma unroll
  for (int i = 0; i < 4; ++i){ acc[i][0] = 0.f; acc[i][1] = 0.f; }
  for (int k0 = 0; k0 < 512; k0 += 32){
    bf16x8 aw[4], bt[2];
    #pragma unroll
    for (int of = 0; of < 4; ++of)
      aw[of] = *(const bf16x8*)(wgate + (size_t)(w*64 + of*16 + l15)*512 + k0 + g*8);
    #pragma unroll
    for (int mf = 0; mf < 2; ++mf)
      bt[mf] = *(const bf16x8*)(&ats[mf*16 + l15][k0 + g*8]);
    #pragma unroll
    for (int of = 0; of < 4; ++of)
      #pragma unroll
      for (int mf = 0; mf < 2; ++mf)
        acc[of][mf] = __builtin_amdgcn_mfma_f32_16x16x32_bf16(aw[of], bt[mf], acc[of][mf], 0, 0, 0);
  }
  #pragma unroll
  for (int of = 0; of < 4; ++of){
    int o4 = w*64 + of*16 + g*4;
    float4 gb4 = *(const float4*)(gate_b + o4);
    #pragma unroll
    for (int mf = 0; mf < 2; ++mf){
      int ml = mf*16 + l15;
      u16x4 ra4 = *(const u16x4*)(&ats[ml][o4]);
      u16x4 da4 = *(const u16x4*)(&ats[ml][256 + o4]);
      #pragma unroll
      for (int r = 0; r < 4; ++r){
        float gg = sigm(acc[of][mf][r] + (&gb4.x)[r]);
        float ra = bf2f(ra4[r]);
        float da = bf2f(da4[r]);
        float fv = ra*gg + da*(1.f - gg) + ra*da;
        fvs[o4 + r][ml] = f2bf(fv);
      }
    }
  }
  __syncthreads();
  {
    int m = threadIdx.x & 31, jg = threadIdx.x >> 5;   // jg 0..7, 3 j each
    const float* w1r0 = w1 + (size_t)(jg*3+0)*256;
    const float* w1r1 = w1 + (size_t)(jg*3+1)*256;
    const float* w1r2 = w1 + (size_t)(jg*3+2)*256;
    float h0 = 0.f, h1 = 0.f, h2 = 0.f;
    for (int c = 0; c < 256; ++c){
      float v = bf2f(fvs[c][m]);
      h0 += w1r0[c]*v; h1 += w1r1[c]*v; h2 += w1r2[c]*v;
    }
    hs[jg*3+0][m] = h0; hs[jg*3+1][m] = h1; hs[jg*3+2][m] = h2;
  }
  __syncthreads();
  if (threadIdx.x < 32){
    int mm = threadIdx.x;
    float s2 = 0.f;
    #pragma unroll
    for (int j = 0; j < 24; ++j){
      float hj = fmaxf(hs[j][mm]*(BN_SC*g1[j]) + b1[j], 0.f);
      s2 += w2[j]*hj;
    }
    s2 = s2*(BN_SC*g2[0]) + b2[0];
    swm[mm] = sigm(sigm(s2));
    ssr[mm] = sa[(size_t)b*N_ + m0 + mm];          // rgb_sa
    ssc[mm] = sa[(size_t)(B_+b)*N_ + m0 + mm];     // chm_sa
  }
  __syncthreads();
  {
    int c8 = threadIdx.x >> 3;          // 0..31
    int p4 = (threadIdx.x & 7)*4;       // 0..28
    for (int pass = 0; pass < 8; ++pass){
      int c = pass*32 + c8;
      float cac = ca[(B_+b)*C_ + c];    // chm_ca
      float car = ca[b*C_ + c];         // rgb_ca
      size_t off = ((size_t)b*C_ + c)*N_ + m0 + p4;
      float4 rv4 = *(const float4*)(rgb + off);
      float4 cv4 = *(const float4*)(chm + off);
      float4 o;
      o.x = rv4.x*ssc[p4+0]*cac + cv4.x*ssr[p4+0]*car*swm[p4+0];
      o.y = rv4.y*ssc[p4+1]*cac + cv4.y*ssr[p4+1]*car*swm[p4+1];
      o.z = rv4.z*ssc[p4+2]*cac + cv4.z*ssr[p4+2]*car*swm[p4+2];
      o.w = rv4.w*ssc[p4+3]*cac + cv4.w*ssr[p4+3]*car*swm[p4+3];
      *(float4*)(out + off) = o;
    }
  }
}

extern "C" void kernel_launch(void* const* d_in, const int* in_sizes, int n_in,
                              void* d_out, int out_size, void* d_ws, size_t ws_size,
                              hipStream_t stream){
  if (ws_size < WS_NEEDED) return;
  const float* rgb      = (const float*)d_in[0];
  const float* chm      = (const float*)d_in[1];
  const float* rgb_sa_w = (const float*)d_in[2];
  const float* rgb_sa_b = (const float*)d_in[3];
  const float* chm_sa_w = (const float*)d_in[4];
  const float* chm_sa_b = (const float*)d_in[5];
  const float* rgb_fc1_w= (const float*)d_in[6];
  const float* rgb_fc1_b= (const float*)d_in[7];
  const float* rgb_fc2_w= (const float*)d_in[8];
  const float* rgb_fc2_b= (const float*)d_in[9];
  const float* chm_fc1_w= (const float*)d_in[10];
  const float* chm_fc1_b= (const float*)d_in[11];
  const float* chm_fc2_w= (const float*)d_in[12];
  const float* chm_fc2_b= (const float*)d_in[13];
  const float* rq_w = (const float*)d_in[14];
  const float* rq_b = (const float*)d_in[15];
  const float* rk_w = (const float*)d_in[16];
  const float* rk_b = (const float*)d_in[17];
  const float* rv_w = (const float*)d_in[18];
  const float* rv_b = (const float*)d_in[19];
  const float* dq_w = (const float*)d_in[20];
  const float* dq_b = (const float*)d_in[21];
  const float* dk_w = (const float*)d_in[22];
  const float* dk_b = (const float*)d_in[23];
  const float* dv_w = (const float*)d_in[24];
  const float* dv_b = (const float*)d_in[25];
  const float* gate_w = (const float*)d_in[26];
  const float* gate_b = (const float*)d_in[27];
  const float* mlp1_w = (const float*)d_in[28];
  const float* mlp1_g = (const float*)d_in[29];
  const float* mlp1_b = (const float*)d_in[30];
  const float* mlp2_w = (const float*)d_in[31];
  const float* mlp2_g = (const float*)d_in[32];
  const float* mlp2_b = (const float*)d_in[33];

  char* ws = (char*)d_ws;
  unsigned short* wsu   = (unsigned short*)d_ws;
  float* sconv = (float*)(ws + OFF_SCONV);
  float* sa    = (float*)(ws + OFF_SA);
  float* ca    = (float*)(ws + OFF_CA);
  float* pcs   = (float*)(ws + OFF_PCS);
  float* pcm   = (float*)(ws + OFF_PCM);
  unsigned short* wproj = (unsigned short*)(ws + OFF_WPROJ);
  unsigned short* wgate = (unsigned short*)(ws + OFF_WGATE);
  unsigned short* att   = (unsigned short*)(ws + OFF_ATT);

  k_prep_w<<<dim3(1152), dim3(256), 0, stream>>>(rq_w, rk_w, rv_w, dq_w, dk_w, dv_w, gate_w, wproj, wgate);
  k_stage<<<dim3(288,2), dim3(256), 0, stream>>>(rgb, chm, wproj, rq_b, rk_b, rv_b, dq_b, dk_b, dv_b,
                                                 wsu, sconv, pcs, pcm);
  k_sa_ca<<<dim3(160), dim3(256), 0, stream>>>(sconv, rgb_sa_w, rgb_sa_b, chm_sa_w, chm_sa_b, sa,
                                               pcs, pcm, rgb_fc1_w, rgb_fc1_b, rgb_fc2_w, rgb_fc2_b,
                                               chm_fc1_w, chm_fc1_b, chm_fc2_w, chm_fc2_b, ca);
  k_phase_a<<<dim3(576), dim3(256), 0, stream>>>(wsu);
  k_pv5<<<dim3(576), dim3(256), 0, stream>>>(wsu, att);
  k_gatemlp<<<dim3(576), dim3(256), 0, stream>>>(att, wgate, gate_b,
                                                  mlp1_w, mlp1_g, mlp1_b, mlp2_w, mlp2_g, mlp2_b,
                                                  rgb, chm, sa, ca, (float*)d_out);
}

// Round 15
// 262.983 us; speedup vs baseline: 1.0031x; 1.0031x over previous
//
#include <hip/hip_runtime.h>
#include <hip/hip_bf16.h>
#include <cstdint>

#define DI __device__ __forceinline__

typedef float f32x4 __attribute__((ext_vector_type(4)));
typedef short bf16x8 __attribute__((ext_vector_type(8)));
typedef unsigned short u16x4 __attribute__((ext_vector_type(4)));

constexpr int B_ = 8, C_ = 256, HH = 48, WW = 48, N_ = 2304, CR = 32;
constexpr float QK_SCALE = 0.17677669529663687f;   // 32^-0.5
constexpr float BN_SC = 0.99999500003749968f;      // 1/sqrt(1+1e-5)

// ---------------- workspace layout (bytes) ----------------
constexpr size_t QK_SZ   = (size_t)B_*N_*CR*2;         // bf16 [B][N][32]
constexpr size_t V_SZ    = (size_t)B_*C_*N_*2;         // bf16 [B][C][N]
constexpr size_t OFF_RQT = 0;
constexpr size_t OFF_RKT = OFF_RQT + QK_SZ;
constexpr size_t OFF_DQT = OFF_RKT + QK_SZ;
constexpr size_t OFF_DKT = OFF_DQT + QK_SZ;
constexpr size_t OFF_RV  = OFF_DKT + QK_SZ;            // scaled in-place by phase_a
constexpr size_t OFF_DV  = OFF_RV + V_SZ;
constexpr size_t OFF_ATT = OFF_DV + V_SZ;              // bf16 [a][b][c][m]  18.9 MB (late)
constexpr size_t ATT_SZ  = 2ull*B_*C_*N_*2;
constexpr size_t OFF_PCS = OFF_ATT;                    // f32 [2][8][36][256] (early, dead before att)
constexpr size_t OFF_PCM = OFF_ATT + 2ull*8*36*256*4;
constexpr size_t OFF_SCONV = OFF_ATT + ATT_SZ;         // f32 [2][B][2][N]
constexpr size_t SCONV_SZ  = 2ull*B_*2*N_*4;
constexpr size_t OFF_SA    = OFF_SCONV + SCONV_SZ;     // f32 [2][B][N]
constexpr size_t SA_SZ     = 2ull*B_*N_*4;
constexpr size_t OFF_CA    = OFF_SA + SA_SZ;           // f32 [2][B][C]
constexpr size_t CST_SZ    = 2ull*B_*C_*4;
constexpr size_t OFF_WPROJ = OFF_CA + CST_SZ;          // bf16 [2][320][256]
constexpr size_t WPROJ_SZ  = 2ull*320*256*2;
constexpr size_t OFF_WGATE = OFF_WPROJ + WPROJ_SZ;     // bf16 [256][512]
constexpr size_t WS_NEEDED = OFF_WGATE + 256ull*512*2;

DI float bf2f(unsigned short u){ union{unsigned int i; float f;} v; v.i = ((unsigned int)u)<<16; return v.f; }
DI unsigned short f2bf(float f){ union{float f; unsigned int i;} v; v.f=f; unsigned int r = v.i + 0x7fffu + ((v.i>>16)&1u); return (unsigned short)(r>>16); }
DI float sigm(float x){ return 1.0f/(1.0f+__expf(-x)); }
DI u16x4 pk4(float p0, float p1, float p2, float p3){
  union { __hip_bfloat162 h[2]; u16x4 v; } u;
  u.h[0] = __float22bfloat162_rn(make_float2(p0, p1));
  u.h[1] = __float22bfloat162_rn(make_float2(p2, p3));
  return u.v;
}

// ---------------- 1. cast/stack weights to bf16 ----------------
__global__ void k_prep_w(const float* rq_w, const float* rk_w, const float* rv_w,
                         const float* dq_w, const float* dk_w, const float* dv_w,
                         const float* gate_w, unsigned short* wproj, unsigned short* wgate){
  int i = blockIdx.x*256 + threadIdx.x;
  if (i < 163840){
    int mod = i / 81920, r = (i >> 8) % 320, c = i & 255;
    const float* q = mod ? dq_w : rq_w;
    const float* k = mod ? dk_w : rk_w;
    const float* v = mod ? dv_w : rv_w;
    float val = (r < 32) ? q[r*256+c] : (r < 64 ? k[(r-32)*256+c] : v[(r-64)*256+c]);
    wproj[i] = f2bf(val);
  } else {
    int j = i - 163840;
    if (j < 131072) wgate[j] = f2bf(gate_w[j]);
  }
}

// ---------------- 2. fused: X one-pass -> reductions + q/k/v projection (XCD-pinned b) ----------------
__global__ __launch_bounds__(256, 2) void k_stage(
                       const float* rgb, const float* chm, const unsigned short* wproj,
                       const float* rq_b, const float* rk_b, const float* rv_b,
                       const float* dq_b, const float* dk_b, const float* dv_b,
                       unsigned short* wsu, float* sconv, float* pcs, float* pcm){
  int mod = blockIdx.y;
  int x = blockIdx.x;
  int b = x & 7, nt = x >> 3;          // XCD pin
  int pix0 = nt*64;
  const float* X = (mod ? chm : rgb) + (size_t)b*C_*N_ + pix0;
  __shared__ unsigned short xs[256*68];   // [ch 256][pix 64] bf16, pitch 68
  __shared__ float ls[4][64], lm[4][64];
  int t = threadIdx.x;
  {
    int srow = t >> 4;           // 0..15
    int scol = (t & 15) * 4;     // 0..60
    #pragma unroll
    for (int rr = 0; rr < 16; ++rr){
      int row = rr*16 + srow;
      float4 v = *(const float4*)(X + (size_t)row*N_ + scol);
      u16x4 h = { f2bf(v.x), f2bf(v.y), f2bf(v.z), f2bf(v.w) };
      *(u16x4*)(xs + row*68 + scol) = h;
    }
  }
  __syncthreads();
  {
    int p = t & 63, cg = t >> 6;
    float s = 0.f, mx = -INFINITY;
    for (int cc = 0; cc < 64; ++cc){
      float v = bf2f(xs[(cg*64+cc)*68 + p]);
      s += v; mx = fmaxf(mx, v);
    }
    ls[cg][p] = s; lm[cg][p] = mx;
  }
  {
    float cs = 0.f, cm = -INFINITY;
    for (int p = 0; p < 64; ++p){
      float v = bf2f(xs[t*68 + p]);
      cs += v; cm = fmaxf(cm, v);
    }
    pcs[((size_t)(mod*8+b)*36 + nt)*256 + t] = cs;
    pcm[((size_t)(mod*8+b)*36 + nt)*256 + t] = cm;
  }
  __syncthreads();
  if (t < 64){
    int p = t;
    float s = ls[0][p]+ls[1][p]+ls[2][p]+ls[3][p];
    float mx = fmaxf(fmaxf(lm[0][p],lm[1][p]), fmaxf(lm[2][p],lm[3][p]));
    sconv[((size_t)(mod*B_+b)*2 + 0)*N_ + pix0+p] = s*(1.f/256.f);
    sconv[((size_t)(mod*B_+b)*2 + 1)*N_ + pix0+p] = mx;
  }
  const unsigned short* Wm = wproj + (size_t)mod*320*256;
  int lane = t & 63, w = t >> 6;
  int l15 = lane & 15, g = lane >> 4;
  f32x4 acc[5][4];
  #pragma unroll
  for (int i = 0; i < 5; ++i)
    #pragma unroll
    for (int j = 0; j < 4; ++j) acc[i][j] = 0.f;
  for (int k0 = 0; k0 < 256; k0 += 32){
    bf16x8 af[5];
    #pragma unroll
    for (int cf = 0; cf < 5; ++cf)
      af[cf] = *(const bf16x8*)(Wm + (size_t)(w*80 + cf*16 + l15)*256 + k0 + g*8);
    bf16x8 bx[4];
    #pragma unroll
    for (int mf = 0; mf < 4; ++mf)
      #pragma unroll
      for (int j = 0; j < 8; ++j)
        bx[mf][j] = (short)xs[(k0 + g*8 + j)*68 + mf*16 + l15];
    #pragma unroll
    for (int cf = 0; cf < 5; ++cf)
      #pragma unroll
      for (int mf = 0; mf < 4; ++mf)
        acc[cf][mf] = __builtin_amdgcn_mfma_f32_16x16x32_bf16(af[cf], bx[mf], acc[cf][mf], 0, 0, 0);
  }
  const float* qb = mod ? dq_b : rq_b;
  const float* kb = mod ? dk_b : rk_b;
  const float* vb = mod ? dv_b : rv_b;
  unsigned short* qT = wsu + (mod ? OFF_DQT : OFF_RQT)/2;
  unsigned short* kT = wsu + (mod ? OFF_DKT : OFF_RKT)/2;
  unsigned short* vB = wsu + (mod ? OFF_DV  : OFF_RV )/2;
  #pragma unroll
  for (int cf = 0; cf < 5; ++cf){
    int base = w*80 + cf*16;
    #pragma unroll
    for (int mf = 0; mf < 4; ++mf){
      int col = pix0 + mf*16 + l15;
      if (base < 32){
        int o4 = base + g*4;
        u16x4 pk = { f2bf(acc[cf][mf][0] + qb[o4]),   f2bf(acc[cf][mf][1] + qb[o4+1]),
                     f2bf(acc[cf][mf][2] + qb[o4+2]), f2bf(acc[cf][mf][3] + qb[o4+3]) };
        *(u16x4*)(qT + (size_t)(b*N_ + col)*32 + o4) = pk;
      } else if (base < 64){
        int o4 = base - 32 + g*4;
        u16x4 pk = { f2bf(acc[cf][mf][0] + kb[o4]),   f2bf(acc[cf][mf][1] + kb[o4+1]),
                     f2bf(acc[cf][mf][2] + kb[o4+2]), f2bf(acc[cf][mf][3] + kb[o4+3]) };
        *(u16x4*)(kT + (size_t)(b*N_ + col)*32 + o4) = pk;
      } else {
        #pragma unroll
        for (int r = 0; r < 4; ++r){
          int o = base - 64 + g*4 + r;
          vB[((size_t)b*C_ + o)*N_ + col] = f2bf(acc[cf][mf][r] + vb[o]);
        }
      }
    }
  }
}

// ---------------- 3. merged 7x7 conv + channel-attn MLP ----------------
__global__ void k_sa_ca(const float* sconv, const float* rgb_sa_w, const float* rgb_sa_b,
                        const float* chm_sa_w, const float* chm_sa_b, float* sa,
                        const float* pcs, const float* pcm,
                        const float* rw1, const float* rb1, const float* rw2, const float* rb2,
                        const float* cw1, const float* cb1, const float* cw2, const float* cb2,
                        float* ca){
  int x = blockIdx.x;
  if (x < 144){
    int mod = x / 72;
    int idx = (x % 72)*256 + threadIdx.x;
    int b = idx / N_, pix = idx % N_;
    int y = pix / WW, xx0 = pix % WW;
    const float* w7 = mod ? chm_sa_w : rgb_sa_w;
    float acc = (mod ? chm_sa_b : rgb_sa_b)[0];
    const float* sin0 = sconv + (size_t)(mod*B_+b)*2*N_;
    #pragma unroll
    for (int ic = 0; ic < 2; ++ic)
      for (int ky = 0; ky < 7; ++ky){
        int yy = y + ky - 3; if (yy < 0 || yy >= HH) continue;
        for (int kx = 0; kx < 7; ++kx){
          int xx = xx0 + kx - 3; if (xx < 0 || xx >= WW) continue;
          acc += w7[(ic*7+ky)*7+kx] * sin0[ic*N_ + yy*WW + xx];
        }
      }
    sa[(mod*B_+b)*N_ + pix] = sigm(acc);
  } else {
    int y = x - 144;
    int mod = y >> 3, b = y & 7;
    const float* w1 = mod ? cw1 : rw1;  const float* b1 = mod ? cb1 : rb1;
    const float* w2 = mod ? cw2 : rw2;  const float* b2 = mod ? cb2 : rb2;
    __shared__ float va[256], vm[256], h1a[16], h1m[16];
    int t = threadIdx.x;
    float s = 0.f, mx = -INFINITY;
    for (int nt = 0; nt < 36; ++nt){
      s += pcs[((size_t)(mod*8+b)*36 + nt)*256 + t];
      mx = fmaxf(mx, pcm[((size_t)(mod*8+b)*36 + nt)*256 + t]);
    }
    va[t] = s*(1.f/(float)N_);
    vm[t] = mx;
    __syncthreads();
    if (t < 32){
      int j = t & 15;
      const float* v = (t >= 16) ? vm : va;
      float ss = b1[j];
      for (int c = 0; c < 256; ++c) ss += w1[j*256+c]*v[c];
      float* hp = (t >= 16) ? h1m : h1a;
      hp[j] = fmaxf(ss, 0.f);
    }
    __syncthreads();
    float fa = b2[t], fm = b2[t];
    #pragma unroll
    for (int j = 0; j < 16; ++j){ fa += w2[t*16+j]*h1a[j]; fm += w2[t*16+j]*h1m[j]; }
    ca[(mod*B_+b)*C_ + t] = sigm(fa + fm);
  }
}

// ---------------- 4. softmax denominators + in-place V scaling (XCD-pinned; warms L2) ----------------
__global__ void k_phase_a(unsigned short* wsu){
  int orig = blockIdx.x;
  int b = orig & 7;
  int logical = orig >> 3;          // 0..71
  int a = logical / 36;
  int nb0 = (logical % 36)*64;
  int lane = threadIdx.x & 63, w = threadIdx.x >> 6;
  int l15 = lane & 15, g = lane >> 4;
  int n0 = nb0 + w*16;
  const unsigned short* Q = wsu + (a ? OFF_DQT : OFF_RQT)/2;
  const unsigned short* K = wsu + (a ? OFF_RKT : OFF_DKT)/2;
  bf16x8 af = *(const bf16x8*)(Q + (size_t)(b*N_ + n0 + l15)*32 + g*8);
  float lrun[4] = {0.f,0.f,0.f,0.f};
  for (int m0 = 0; m0 < N_; m0 += 64){
    f32x4 d[4];
    #pragma unroll
    for (int s = 0; s < 4; ++s){
      bf16x8 bk = *(const bf16x8*)(K + (size_t)(b*N_ + m0 + s*16 + l15)*32 + g*8);
      f32x4 z = 0.f;
      d[s] = __builtin_amdgcn_mfma_f32_16x16x32_bf16(af, bk, z, 0, 0, 0);
    }
    #pragma unroll
    for (int r = 0; r < 4; ++r)
      lrun[r] += (__expf(d[0][r]*QK_SCALE)+__expf(d[1][r]*QK_SCALE))
               + (__expf(d[2][r]*QK_SCALE)+__expf(d[3][r]*QK_SCALE));
  }
  #pragma unroll
  for (int r = 0; r < 4; ++r)
    #pragma unroll
    for (int msk = 1; msk < 16; msk <<= 1) lrun[r] += __shfl_xor(lrun[r], msk);
  __shared__ float lsv[64];
  if (l15 == 0){
    #pragma unroll
    for (int r = 0; r < 4; ++r) lsv[w*16 + g*4 + r] = 1.0f / lrun[r];
  }
  __syncthreads();
  unsigned short* V = wsu + (a ? OFF_DV : OFF_RV)/2 + ((size_t)b*C_ + threadIdx.x)*N_ + nb0;
  #pragma unroll
  for (int j8 = 0; j8 < 8; ++j8){
    bf16x8 vv = *(const bf16x8*)(V + j8*8);
    bf16x8 ov;
    #pragma unroll
    for (int e = 0; e < 8; ++e)
      ov[e] = (short)f2bf(bf2f((unsigned short)vv[e]) * lsv[j8*8 + e]);
    *(bf16x8*)(V + j8*8) = ov;
  }
}

// ---------------- 5. PV: m64 full-C, BN=192/interval (12 intervals) ----------------
__global__ __launch_bounds__(256, 3) void k_pv5(
                          const unsigned short* wsu, unsigned short* att){
  int orig = blockIdx.x;
  int logical = (orig & 7)*72 + (orig >> 3);
  int pair = logical / 36, mblk = logical % 36;
  int a = pair >> 3, b = pair & 7;
  int m0 = mblk*64;
  int lane = threadIdx.x & 63, w = threadIdx.x >> 6;
  int l15 = lane & 15, g = lane >> 4;
  int qm  = (w & 1)*32;     // this wave's P m-offset
  int qnn = (w >> 1)*96;    // this wave's P n-offset (within 192)
  const unsigned short* Q = wsu + (a ? OFF_DQT : OFF_RQT)/2;
  const unsigned short* K = wsu + (a ? OFF_RKT : OFF_DKT)/2;
  const unsigned short* V = wsu + (a ? OFF_DV  : OFF_RV )/2;   // pre-scaled by 1/D
  __shared__ __align__(16) unsigned char plds[2][64*384];  // [buf][m 64][384B], xor swizzle

  bf16x8 kb[2];
  #pragma unroll
  for (int s = 0; s < 2; ++s)
    kb[s] = *(const bf16x8*)(K + (size_t)(b*N_ + m0 + qm + s*16 + l15)*32 + g*8);

  f32x4 acc[4][4];
  #pragma unroll
  for (int i = 0; i < 4; ++i)
    #pragma unroll
    for (int j = 0; j < 4; ++j) acc[i][j] = 0.f;

  // write this wave's P[qm..+32][qnn + half*32 .. +32] for tile at n0base
  auto computePh = [&](int n0base, int buf, int half){
    #pragma unroll
    for (int fi = 0; fi < 2; ++fi){
      int fr = half*2 + fi;
      int nb = n0base + qnn + fr*16;
      bf16x8 qa = *(const bf16x8*)(Q + (size_t)(b*N_ + nb + l15)*32 + g*8);
      #pragma unroll
      for (int fm = 0; fm < 2; ++fm){
        f32x4 z = 0.f;
        f32x4 d = __builtin_amdgcn_mfma_f32_16x16x32_bf16(qa, kb[fm], z, 0, 0, 0);
        int ml = qm + fm*16 + l15;
        int nl = qnn + fr*16 + g*4;
        u16x4 pk = pk4(__expf(d[0]*QK_SCALE), __expf(d[1]*QK_SCALE),
                       __expf(d[2]*QK_SCALE), __expf(d[3]*QK_SCALE));
        *(u16x4*)(plds[buf] + ml*384 + ((nl*2) ^ ((ml&15)<<4))) = pk;
      }
    }
  };

  const unsigned short* Vb = V + ((size_t)b*C_ + w*64 + l15)*N_;   // + cf*16*N_ + n

  computePh(0, 0, 0);
  computePh(0, 0, 1);
  computePh(0, 0, 2);
  __syncthreads();
  for (int t = 0; t < 12; ++t){
    int n0 = t*192;
    const unsigned char* pbuf = plds[t & 1];
    bf16x8 av[2][4];
    #pragma unroll
    for (int ss = 0; ss < 2; ++ss)
      #pragma unroll
      for (int cf = 0; cf < 4; ++cf)
        av[ss][cf] = *(const bf16x8*)(Vb + (size_t)cf*16*N_ + n0 + ss*32 + g*8);
    #pragma unroll
    for (int s = 0; s < 6; ++s){
      bf16x8 pb[4];
      #pragma unroll
      for (int mf = 0; mf < 4; ++mf){
        int ml = mf*16 + l15;
        pb[mf] = *(const bf16x8*)(pbuf + ml*384 + ((s*64 + g*16) ^ ((ml&15)<<4)));
      }
      if (t < 11 && s < 3) computePh(n0 + 192, (t+1)&1, s);
      __builtin_amdgcn_s_setprio(1);
      #pragma unroll
      for (int cf = 0; cf < 4; ++cf)
        #pragma unroll
        for (int mf = 0; mf < 4; ++mf)
          acc[cf][mf] = __builtin_amdgcn_mfma_f32_16x16x32_bf16(av[s&1][cf], pb[mf], acc[cf][mf], 0, 0, 0);
      __builtin_amdgcn_s_setprio(0);
      if (s < 4){
        #pragma unroll
        for (int cf = 0; cf < 4; ++cf)
          av[s&1][cf] = *(const bf16x8*)(Vb + (size_t)cf*16*N_ + n0 + (s+2)*32 + g*8);
      }
    }
    __syncthreads();
  }
  unsigned short* ap = att + (((size_t)a*8 + b)*256)*N_;
  #pragma unroll
  for (int cf = 0; cf < 4; ++cf)
    #pragma unroll
    for (int mf = 0; mf < 4; ++mf)
      #pragma unroll
      for (int r = 0; r < 4; ++r){
        int c = w*64 + cf*16 + g*4 + r;
        int m = m0 + mf*16 + l15;
        ap[(size_t)c*N_ + m] = f2bf(acc[cf][mf][r]);
      }
}

// ---------------- 6. gate GEMM + fuse + MLP + final combine (XCD-pinned b) ----------------
__global__ __launch_bounds__(256, 2) void k_gatemlp(
                           const unsigned short* att, const unsigned short* wgate,
                           const float* gate_b,
                           const float* w1, const float* g1, const float* b1,
                           const float* w2, const float* g2, const float* b2,
                           const float* rgb, const float* chm, const float* sa, const float* ca,
                           float* out){
  int orig = blockIdx.x;
  int b = orig & 7, m0 = (orig >> 3)*32;
  int lane = threadIdx.x & 63, w = threadIdx.x >> 6;
  int l15 = lane & 15, g = lane >> 4;
  __shared__ unsigned short ats[32][520];   // [m local][k = a*256+c]
  __shared__ unsigned short fvs[256][34];   // [c][m local] bf16
  __shared__ float hs[24][33];
  __shared__ float swm[32], ssr[32], ssc[32];
  int row8 = threadIdx.x >> 3;      // 0..31
  int mq = (threadIdx.x & 7)*4;     // m offset
  for (int rb = 0; rb < 16; ++rb){
    int k = rb*32 + row8;           // 0..511
    int aa = k >> 8, c = k & 255;
    size_t base = (((size_t)aa*8 + b)*256 + c)*N_ + m0 + mq;
    u16x4 p0 = *(const u16x4*)(att + base);
    #pragma unroll
    for (int j = 0; j < 4; ++j) ats[mq + j][k] = p0[j];
  }
  __syncthreads();
  f32x4 acc[4][2];
  #pragma unroll
  for (int i = 0; i < 4; ++i){ acc[i][0] = 0.f; acc[i][1] = 0.f; }
  for (int k0 = 0; k0 < 512; k0 += 32){
    bf16x8 aw[4], bt[2];
    #pragma unroll
    for (int of = 0; of < 4; ++of)
      aw[of] = *(const bf16x8*)(wgate + (size_t)(w*64 + of*16 + l15)*512 + k0 + g*8);
    #pragma unroll
    for (int mf = 0; mf < 2; ++mf)
      bt[mf] = *(const bf16x8*)(&ats[mf*16 + l15][k0 + g*8]);
    #pragma unroll
    for (int of = 0; of < 4; ++of)
      #pragma unroll
      for (int mf = 0; mf < 2; ++mf)
        acc[of][mf] = __builtin_amdgcn_mfma_f32_16x16x32_bf16(aw[of], bt[mf], acc[of][mf], 0, 0, 0);
  }
  #pragma unroll
  for (int of = 0; of < 4; ++of){
    int o4 = w*64 + of*16 + g*4;
    float4 gb4 = *(const float4*)(gate_b + o4);
    #pragma unroll
    for (int mf = 0; mf < 2; ++mf){
      int ml = mf*16 + l15;
      u16x4 ra4 = *(const u16x4*)(&ats[ml][o4]);
      u16x4 da4 = *(const u16x4*)(&ats[ml][256 + o4]);
      #pragma unroll
      for (int r = 0; r < 4; ++r){
        float gg = sigm(acc[of][mf][r] + (&gb4.x)[r]);
        float ra = bf2f(ra4[r]);
        float da = bf2f(da4[r]);
        float fv = ra*gg + da*(1.f - gg) + ra*da;
        fvs[o4 + r][ml] = f2bf(fv);
      }
    }
  }
  __syncthreads();
  {
    int m = threadIdx.x & 31, jg = threadIdx.x >> 5;   // jg 0..7, 3 j each
    const float* w1r0 = w1 + (size_t)(jg*3+0)*256;
    const float* w1r1 = w1 + (size_t)(jg*3+1)*256;
    const float* w1r2 = w1 + (size_t)(jg*3+2)*256;
    float h0 = 0.f, h1 = 0.f, h2 = 0.f;
    for (int c = 0; c < 256; ++c){
      float v = bf2f(fvs[c][m]);
      h0 += w1r0[c]*v; h1 += w1r1[c]*v; h2 += w1r2[c]*v;
    }
    hs[jg*3+0][m] = h0; hs[jg*3+1][m] = h1; hs[jg*3+2][m] = h2;
  }
  __syncthreads();
  if (threadIdx.x < 32){
    int mm = threadIdx.x;
    float s2 = 0.f;
    #pragma unroll
    for (int j = 0; j < 24; ++j){
      float hj = fmaxf(hs[j][mm]*(BN_SC*g1[j]) + b1[j], 0.f);
      s2 += w2[j]*hj;
    }
    s2 = s2*(BN_SC*g2[0]) + b2[0];
    swm[mm] = sigm(sigm(s2));
    ssr[mm] = sa[(size_t)b*N_ + m0 + mm];          // rgb_sa
    ssc[mm] = sa[(size_t)(B_+b)*N_ + m0 + mm];     // chm_sa
  }
  __syncthreads();
  {
    int c8 = threadIdx.x >> 3;          // 0..31
    int p4 = (threadIdx.x & 7)*4;       // 0..28
    for (int pass = 0; pass < 8; ++pass){
      int c = pass*32 + c8;
      float cac = ca[(B_+b)*C_ + c];    // chm_ca
      float car = ca[b*C_ + c];         // rgb_ca
      size_t off = ((size_t)b*C_ + c)*N_ + m0 + p4;
      float4 rv4 = *(const float4*)(rgb + off);
      float4 cv4 = *(const float4*)(chm + off);
      float4 o;
      o.x = rv4.x*ssc[p4+0]*cac + cv4.x*ssr[p4+0]*car*swm[p4+0];
      o.y = rv4.y*ssc[p4+1]*cac + cv4.y*ssr[p4+1]*car*swm[p4+1];
      o.z = rv4.z*ssc[p4+2]*cac + cv4.z*ssr[p4+2]*car*swm[p4+2];
      o.w = rv4.w*ssc[p4+3]*cac + cv4.w*ssr[p4+3]*car*swm[p4+3];
      *(float4*)(out + off) = o;
    }
  }
}

extern "C" void kernel_launch(void* const* d_in, const int* in_sizes, int n_in,
                              void* d_out, int out_size, void* d_ws, size_t ws_size,
                              hipStream_t stream){
  if (ws_size < WS_NEEDED) return;
  const float* rgb      = (const float*)d_in[0];
  const float* chm      = (const float*)d_in[1];
  const float* rgb_sa_w = (const float*)d_in[2];
  const float* rgb_sa_b = (const float*)d_in[3];
  const float* chm_sa_w = (const float*)d_in[4];
  const float* chm_sa_b = (const float*)d_in[5];
  const float* rgb_fc1_w= (const float*)d_in[6];
  const float* rgb_fc1_b= (const float*)d_in[7];
  const float* rgb_fc2_w= (const float*)d_in[8];
  const float* rgb_fc2_b= (const float*)d_in[9];
  const float* chm_fc1_w= (const float*)d_in[10];
  const float* chm_fc1_b= (const float*)d_in[11];
  const float* chm_fc2_w= (const float*)d_in[12];
  const float* chm_fc2_b= (const float*)d_in[13];
  const float* rq_w = (const float*)d_in[14];
  const float* rq_b = (const float*)d_in[15];
  const float* rk_w = (const float*)d_in[16];
  const float* rk_b = (const float*)d_in[17];
  const float* rv_w = (const float*)d_in[18];
  const float* rv_b = (const float*)d_in[19];
  const float* dq_w = (const float*)d_in[20];
  const float* dq_b = (const float*)d_in[21];
  const float* dk_w = (const float*)d_in[22];
  const float* dk_b = (const float*)d_in[23];
  const float* dv_w = (const float*)d_in[24];
  const float* dv_b = (const float*)d_in[25];
  const float* gate_w = (const float*)d_in[26];
  const float* gate_b = (const float*)d_in[27];
  const float* mlp1_w = (const float*)d_in[28];
  const float* mlp1_g = (const float*)d_in[29];
  const float* mlp1_b = (const float*)d_in[30];
  const float* mlp2_w = (const float*)d_in[31];
  const float* mlp2_g = (const float*)d_in[32];
  const float* mlp2_b = (const float*)d_in[33];

  char* ws = (char*)d_ws;
  unsigned short* wsu   = (unsigned short*)d_ws;
  float* sconv = (float*)(ws + OFF_SCONV);
  float* sa    = (float*)(ws + OFF_SA);
  float* ca    = (float*)(ws + OFF_CA);
  float* pcs   = (float*)(ws + OFF_PCS);
  float* pcm   = (float*)(ws + OFF_PCM);
  unsigned short* wproj = (unsigned short*)(ws + OFF_WPROJ);
  unsigned short* wgate = (unsigned short*)(ws + OFF_WGATE);
  unsigned short* att   = (unsigned short*)(ws + OFF_ATT);

  k_prep_w<<<dim3(1152), dim3(256), 0, stream>>>(rq_w, rk_w, rv_w, dq_w, dk_w, dv_w, gate_w, wproj, wgate);
  k_stage<<<dim3(288,2), dim3(256), 0, stream>>>(rgb, chm, wproj, rq_b, rk_b, rv_b, dq_b, dk_b, dv_b,
                                                 wsu, sconv, pcs, pcm);
  k_sa_ca<<<dim3(160), dim3(256), 0, stream>>>(sconv, rgb_sa_w, rgb_sa_b, chm_sa_w, chm_sa_b, sa,
                                               pcs, pcm, rgb_fc1_w, rgb_fc1_b, rgb_fc2_w, rgb_fc2_b,
                                               chm_fc1_w, chm_fc1_b, chm_fc2_w, chm_fc2_b, ca);
  k_phase_a<<<dim3(576), dim3(256), 0, stream>>>(wsu);
  k_pv5<<<dim3(576), dim3(256), 0, stream>>>(wsu, att);
  k_gatemlp<<<dim3(576), dim3(256), 0, stream>>>(att, wgate, gate_b,
                                                  mlp1_w, mlp1_g, mlp1_b, mlp2_w, mlp2_g, mlp2_b,
                                                  rgb, chm, sa, ca, (float*)d_out);
}

// Round 16
// 259.505 us; speedup vs baseline: 1.0166x; 1.0134x over previous
//
#include <hip/hip_runtime.h>
#include <hip/hip_bf16.h>
#include <cstdint>

#define DI __device__ __forceinline__

typedef float f32x4 __attribute__((ext_vector_type(4)));
typedef short bf16x8 __attribute__((ext_vector_type(8)));
typedef unsigned short u16x4 __attribute__((ext_vector_type(4)));

constexpr int B_ = 8, C_ = 256, HH = 48, WW = 48, N_ = 2304, CR = 32;
constexpr float QK_SCALE = 0.17677669529663687f;   // 32^-0.5
constexpr float BN_SC = 0.99999500003749968f;      // 1/sqrt(1+1e-5)

// ---------------- workspace layout (bytes) ----------------
constexpr size_t QK_SZ   = (size_t)B_*N_*CR*2;         // bf16 [B][N][32]
constexpr size_t V_SZ    = (size_t)B_*C_*N_*2;         // bf16 [B][C][N]
constexpr size_t OFF_RQT = 0;
constexpr size_t OFF_RKT = OFF_RQT + QK_SZ;
constexpr size_t OFF_DQT = OFF_RKT + QK_SZ;
constexpr size_t OFF_DKT = OFF_DQT + QK_SZ;
constexpr size_t OFF_RV  = OFF_DKT + QK_SZ;            // scaled in-place by phase_a
constexpr size_t OFF_DV  = OFF_RV + V_SZ;
constexpr size_t OFF_ATT = OFF_DV + V_SZ;              // bf16 [a][b][c][m]  18.9 MB (late)
constexpr size_t ATT_SZ  = 2ull*B_*C_*N_*2;
constexpr size_t OFF_PCS = OFF_ATT;                    // f32 [2][8][36][256] (early, dead before att)
constexpr size_t OFF_PCM = OFF_ATT + 2ull*8*36*256*4;
constexpr size_t OFF_SCONV = OFF_ATT + ATT_SZ;         // f32 [2][B][2][N]
constexpr size_t SCONV_SZ  = 2ull*B_*2*N_*4;
constexpr size_t OFF_SA    = OFF_SCONV + SCONV_SZ;     // f32 [2][B][N]
constexpr size_t SA_SZ     = 2ull*B_*N_*4;
constexpr size_t OFF_CA    = OFF_SA + SA_SZ;           // f32 [2][B][C]
constexpr size_t CST_SZ    = 2ull*B_*C_*4;
constexpr size_t OFF_WMAP  = OFF_CA + CST_SZ;          // f32 [B][N]
constexpr size_t OFF_WPROJ = OFF_WMAP + (size_t)B_*N_*4;  // bf16 [2][320][256]
constexpr size_t WPROJ_SZ  = 2ull*320*256*2;
constexpr size_t OFF_WGATE = OFF_WPROJ + WPROJ_SZ;     // bf16 [256][512]
constexpr size_t WS_NEEDED = OFF_WGATE + 256ull*512*2;

DI float bf2f(unsigned short u){ union{unsigned int i; float f;} v; v.i = ((unsigned int)u)<<16; return v.f; }
DI unsigned short f2bf(float f){ union{float f; unsigned int i;} v; v.f=f; unsigned int r = v.i + 0x7fffu + ((v.i>>16)&1u); return (unsigned short)(r>>16); }
DI float sigm(float x){ return 1.0f/(1.0f+__expf(-x)); }
DI u16x4 pk4(float p0, float p1, float p2, float p3){
  union { __hip_bfloat162 h[2]; u16x4 v; } u;
  u.h[0] = __float22bfloat162_rn(make_float2(p0, p1));
  u.h[1] = __float22bfloat162_rn(make_float2(p2, p3));
  return u.v;
}

// ---------------- 1. cast/stack weights to bf16 ----------------
__global__ void k_prep_w(const float* rq_w, const float* rk_w, const float* rv_w,
                         const float* dq_w, const float* dk_w, const float* dv_w,
                         const float* gate_w, unsigned short* wproj, unsigned short* wgate){
  int i = blockIdx.x*256 + threadIdx.x;
  if (i < 163840){
    int mod = i / 81920, r = (i >> 8) % 320, c = i & 255;
    const float* q = mod ? dq_w : rq_w;
    const float* k = mod ? dk_w : rk_w;
    const float* v = mod ? dv_w : rv_w;
    float val = (r < 32) ? q[r*256+c] : (r < 64 ? k[(r-32)*256+c] : v[(r-64)*256+c]);
    wproj[i] = f2bf(val);
  } else {
    int j = i - 163840;
    if (j < 131072) wgate[j] = f2bf(gate_w[j]);
  }
}

// ---------------- 2. fused: X one-pass -> reductions + q/k/v projection (XCD-pinned b) ----------------
__global__ __launch_bounds__(256, 2) void k_stage(
                       const float* rgb, const float* chm, const unsigned short* wproj,
                       const float* rq_b, const float* rk_b, const float* rv_b,
                       const float* dq_b, const float* dk_b, const float* dv_b,
                       unsigned short* wsu, float* sconv, float* pcs, float* pcm){
  int mod = blockIdx.y;
  int x = blockIdx.x;
  int b = x & 7, nt = x >> 3;          // XCD pin
  int pix0 = nt*64;
  const float* X = (mod ? chm : rgb) + (size_t)b*C_*N_ + pix0;
  __shared__ unsigned short xs[256*68];   // [ch 256][pix 64] bf16, pitch 68
  __shared__ float ls[4][64], lm[4][64];
  int t = threadIdx.x;
  {
    int srow = t >> 4;           // 0..15
    int scol = (t & 15) * 4;     // 0..60
    #pragma unroll
    for (int rr = 0; rr < 16; ++rr){
      int row = rr*16 + srow;
      float4 v = *(const float4*)(X + (size_t)row*N_ + scol);
      u16x4 h = { f2bf(v.x), f2bf(v.y), f2bf(v.z), f2bf(v.w) };
      *(u16x4*)(xs + row*68 + scol) = h;
    }
  }
  __syncthreads();
  {
    int p = t & 63, cg = t >> 6;
    float s = 0.f, mx = -INFINITY;
    for (int cc = 0; cc < 64; ++cc){
      float v = bf2f(xs[(cg*64+cc)*68 + p]);
      s += v; mx = fmaxf(mx, v);
    }
    ls[cg][p] = s; lm[cg][p] = mx;
  }
  {
    float cs = 0.f, cm = -INFINITY;
    for (int p = 0; p < 64; ++p){
      float v = bf2f(xs[t*68 + p]);
      cs += v; cm = fmaxf(cm, v);
    }
    pcs[((size_t)(mod*8+b)*36 + nt)*256 + t] = cs;
    pcm[((size_t)(mod*8+b)*36 + nt)*256 + t] = cm;
  }
  __syncthreads();
  if (t < 64){
    int p = t;
    float s = ls[0][p]+ls[1][p]+ls[2][p]+ls[3][p];
    float mx = fmaxf(fmaxf(lm[0][p],lm[1][p]), fmaxf(lm[2][p],lm[3][p]));
    sconv[((size_t)(mod*B_+b)*2 + 0)*N_ + pix0+p] = s*(1.f/256.f);
    sconv[((size_t)(mod*B_+b)*2 + 1)*N_ + pix0+p] = mx;
  }
  const unsigned short* Wm = wproj + (size_t)mod*320*256;
  int lane = t & 63, w = t >> 6;
  int l15 = lane & 15, g = lane >> 4;
  f32x4 acc[5][4];
  #pragma unroll
  for (int i = 0; i < 5; ++i)
    #pragma unroll
    for (int j = 0; j < 4; ++j) acc[i][j] = 0.f;
  for (int k0 = 0; k0 < 256; k0 += 32){
    bf16x8 af[5];
    #pragma unroll
    for (int cf = 0; cf < 5; ++cf)
      af[cf] = *(const bf16x8*)(Wm + (size_t)(w*80 + cf*16 + l15)*256 + k0 + g*8);
    bf16x8 bx[4];
    #pragma unroll
    for (int mf = 0; mf < 4; ++mf)
      #pragma unroll
      for (int j = 0; j < 8; ++j)
        bx[mf][j] = (short)xs[(k0 + g*8 + j)*68 + mf*16 + l15];
    #pragma unroll
    for (int cf = 0; cf < 5; ++cf)
      #pragma unroll
      for (int mf = 0; mf < 4; ++mf)
        acc[cf][mf] = __builtin_amdgcn_mfma_f32_16x16x32_bf16(af[cf], bx[mf], acc[cf][mf], 0, 0, 0);
  }
  const float* qb = mod ? dq_b : rq_b;
  const float* kb = mod ? dk_b : rk_b;
  const float* vb = mod ? dv_b : rv_b;
  unsigned short* qT = wsu + (mod ? OFF_DQT : OFF_RQT)/2;
  unsigned short* kT = wsu + (mod ? OFF_DKT : OFF_RKT)/2;
  unsigned short* vB = wsu + (mod ? OFF_DV  : OFF_RV )/2;
  #pragma unroll
  for (int cf = 0; cf < 5; ++cf){
    int base = w*80 + cf*16;
    #pragma unroll
    for (int mf = 0; mf < 4; ++mf){
      int col = pix0 + mf*16 + l15;
      if (base < 32){
        int o4 = base + g*4;
        u16x4 pk = { f2bf(acc[cf][mf][0] + qb[o4]),   f2bf(acc[cf][mf][1] + qb[o4+1]),
                     f2bf(acc[cf][mf][2] + qb[o4+2]), f2bf(acc[cf][mf][3] + qb[o4+3]) };
        *(u16x4*)(qT + (size_t)(b*N_ + col)*32 + o4) = pk;
      } else if (base < 64){
        int o4 = base - 32 + g*4;
        u16x4 pk = { f2bf(acc[cf][mf][0] + kb[o4]),   f2bf(acc[cf][mf][1] + kb[o4+1]),
                     f2bf(acc[cf][mf][2] + kb[o4+2]), f2bf(acc[cf][mf][3] + kb[o4+3]) };
        *(u16x4*)(kT + (size_t)(b*N_ + col)*32 + o4) = pk;
      } else {
        #pragma unroll
        for (int r = 0; r < 4; ++r){
          int o = base - 64 + g*4 + r;
          vB[((size_t)b*C_ + o)*N_ + col] = f2bf(acc[cf][mf][r] + vb[o]);
        }
      }
    }
  }
}

// ---------------- 3. merged 7x7 conv + channel-attn MLP ----------------
__global__ void k_sa_ca(const float* sconv, const float* rgb_sa_w, const float* rgb_sa_b,
                        const float* chm_sa_w, const float* chm_sa_b, float* sa,
                        const float* pcs, const float* pcm,
                        const float* rw1, const float* rb1, const float* rw2, const float* rb2,
                        const float* cw1, const float* cb1, const float* cw2, const float* cb2,
                        float* ca){
  int x = blockIdx.x;
  if (x < 144){
    int mod = x / 72;
    int idx = (x % 72)*256 + threadIdx.x;
    int b = idx / N_, pix = idx % N_;
    int y = pix / WW, xx0 = pix % WW;
    const float* w7 = mod ? chm_sa_w : rgb_sa_w;
    float acc = (mod ? chm_sa_b : rgb_sa_b)[0];
    const float* sin0 = sconv + (size_t)(mod*B_+b)*2*N_;
    #pragma unroll
    for (int ic = 0; ic < 2; ++ic)
      for (int ky = 0; ky < 7; ++ky){
        int yy = y + ky - 3; if (yy < 0 || yy >= HH) continue;
        for (int kx = 0; kx < 7; ++kx){
          int xx = xx0 + kx - 3; if (xx < 0 || xx >= WW) continue;
          acc += w7[(ic*7+ky)*7+kx] * sin0[ic*N_ + yy*WW + xx];
        }
      }
    sa[(mod*B_+b)*N_ + pix] = sigm(acc);
  } else {
    int y = x - 144;
    int mod = y >> 3, b = y & 7;
    const float* w1 = mod ? cw1 : rw1;  const float* b1 = mod ? cb1 : rb1;
    const float* w2 = mod ? cw2 : rw2;  const float* b2 = mod ? cb2 : rb2;
    __shared__ float va[256], vm[256], h1a[16], h1m[16];
    int t = threadIdx.x;
    float s = 0.f, mx = -INFINITY;
    for (int nt = 0; nt < 36; ++nt){
      s += pcs[((size_t)(mod*8+b)*36 + nt)*256 + t];
      mx = fmaxf(mx, pcm[((size_t)(mod*8+b)*36 + nt)*256 + t]);
    }
    va[t] = s*(1.f/(float)N_);
    vm[t] = mx;
    __syncthreads();
    if (t < 32){
      int j = t & 15;
      const float* v = (t >= 16) ? vm : va;
      float ss = b1[j];
      for (int c = 0; c < 256; ++c) ss += w1[j*256+c]*v[c];
      float* hp = (t >= 16) ? h1m : h1a;
      hp[j] = fmaxf(ss, 0.f);
    }
    __syncthreads();
    float fa = b2[t], fm = b2[t];
    #pragma unroll
    for (int j = 0; j < 16; ++j){ fa += w2[t*16+j]*h1a[j]; fm += w2[t*16+j]*h1m[j]; }
    ca[(mod*B_+b)*C_ + t] = sigm(fa + fm);
  }
}

// ---------------- 4. softmax denominators + in-place V scaling (XCD-pinned; warms L2) ----------------
__global__ void k_phase_a(unsigned short* wsu){
  int orig = blockIdx.x;
  int b = orig & 7;
  int logical = orig >> 3;          // 0..71
  int a = logical / 36;
  int nb0 = (logical % 36)*64;
  int lane = threadIdx.x & 63, w = threadIdx.x >> 6;
  int l15 = lane & 15, g = lane >> 4;
  int n0 = nb0 + w*16;
  const unsigned short* Q = wsu + (a ? OFF_DQT : OFF_RQT)/2;
  const unsigned short* K = wsu + (a ? OFF_RKT : OFF_DKT)/2;
  bf16x8 af = *(const bf16x8*)(Q + (size_t)(b*N_ + n0 + l15)*32 + g*8);
  float lrun[4] = {0.f,0.f,0.f,0.f};
  for (int m0 = 0; m0 < N_; m0 += 64){
    f32x4 d[4];
    #pragma unroll
    for (int s = 0; s < 4; ++s){
      bf16x8 bk = *(const bf16x8*)(K + (size_t)(b*N_ + m0 + s*16 + l15)*32 + g*8);
      f32x4 z = 0.f;
      d[s] = __builtin_amdgcn_mfma_f32_16x16x32_bf16(af, bk, z, 0, 0, 0);
    }
    #pragma unroll
    for (int r = 0; r < 4; ++r)
      lrun[r] += (__expf(d[0][r]*QK_SCALE)+__expf(d[1][r]*QK_SCALE))
               + (__expf(d[2][r]*QK_SCALE)+__expf(d[3][r]*QK_SCALE));
  }
  #pragma unroll
  for (int r = 0; r < 4; ++r)
    #pragma unroll
    for (int msk = 1; msk < 16; msk <<= 1) lrun[r] += __shfl_xor(lrun[r], msk);
  __shared__ float lsv[64];
  if (l15 == 0){
    #pragma unroll
    for (int r = 0; r < 4; ++r) lsv[w*16 + g*4 + r] = 1.0f / lrun[r];
  }
  __syncthreads();
  unsigned short* V = wsu + (a ? OFF_DV : OFF_RV)/2 + ((size_t)b*C_ + threadIdx.x)*N_ + nb0;
  #pragma unroll
  for (int j8 = 0; j8 < 8; ++j8){
    bf16x8 vv = *(const bf16x8*)(V + j8*8);
    bf16x8 ov;
    #pragma unroll
    for (int e = 0; e < 8; ++e)
      ov[e] = (short)f2bf(bf2f((unsigned short)vv[e]) * lsv[j8*8 + e]);
    *(bf16x8*)(V + j8*8) = ov;
  }
}

// ---------------- 5. PV: m64 full-C, BN=128/interval, fixed swizzle + V pipeline ----------------
__global__ __launch_bounds__(256, 3) void k_pv5(
                          const unsigned short* wsu, unsigned short* att){
  int orig = blockIdx.x;
  int logical = (orig & 7)*72 + (orig >> 3);
  int pair = logical / 36, mblk = logical % 36;
  int a = pair >> 3, b = pair & 7;
  int m0 = mblk*64;
  int lane = threadIdx.x & 63, w = threadIdx.x >> 6;
  int l15 = lane & 15, g = lane >> 4;
  int qm  = (w & 1)*32;     // this wave's P m-offset
  int qnn = (w >> 1)*64;    // this wave's P n-offset (within 128)
  const unsigned short* Q = wsu + (a ? OFF_DQT : OFF_RQT)/2;
  const unsigned short* K = wsu + (a ? OFF_RKT : OFF_DKT)/2;
  const unsigned short* V = wsu + (a ? OFF_DV  : OFF_RV )/2;   // pre-scaled by 1/D
  __shared__ __align__(16) unsigned char plds[2][64*256];  // [buf][m 64][256B], xor swizzle

  bf16x8 kb[2];
  #pragma unroll
  for (int s = 0; s < 2; ++s)
    kb[s] = *(const bf16x8*)(K + (size_t)(b*N_ + m0 + qm + s*16 + l15)*32 + g*8);

  f32x4 acc[4][4];
  #pragma unroll
  for (int i = 0; i < 4; ++i)
    #pragma unroll
    for (int j = 0; j < 4; ++j) acc[i][j] = 0.f;

  auto computePh = [&](int n0base, int buf, int half){
    #pragma unroll
    for (int fi = 0; fi < 2; ++fi){
      int fr = half*2 + fi;
      int nb = n0base + qnn + fr*16;
      bf16x8 qa = *(const bf16x8*)(Q + (size_t)(b*N_ + nb + l15)*32 + g*8);
      #pragma unroll
      for (int fm = 0; fm < 2; ++fm){
        f32x4 z = 0.f;
        f32x4 d = __builtin_amdgcn_mfma_f32_16x16x32_bf16(qa, kb[fm], z, 0, 0, 0);
        int ml = qm + fm*16 + l15;
        int nl = qnn + fr*16 + g*4;
        u16x4 pk = pk4(__expf(d[0]*QK_SCALE), __expf(d[1]*QK_SCALE),
                       __expf(d[2]*QK_SCALE), __expf(d[3]*QK_SCALE));
        *(u16x4*)(plds[buf] + ml*256 + ((nl*2) ^ ((ml&15)<<4))) = pk;
      }
    }
  };

  const unsigned short* Vb = V + ((size_t)b*C_ + w*64 + l15)*N_;   // + cf*16*N_ + n

  computePh(0, 0, 0);
  computePh(0, 0, 1);
  __syncthreads();
  for (int t = 0; t < 18; ++t){
    int n0 = t*128;
    const unsigned char* pbuf = plds[t & 1];
    bf16x8 av[2][4];
    #pragma unroll
    for (int ss = 0; ss < 2; ++ss)
      #pragma unroll
      for (int cf = 0; cf < 4; ++cf)
        av[ss][cf] = *(const bf16x8*)(Vb + (size_t)cf*16*N_ + n0 + ss*32 + g*8);
    #pragma unroll
    for (int s = 0; s < 4; ++s){
      bf16x8 pb[4];
      #pragma unroll
      for (int mf = 0; mf < 4; ++mf){
        int ml = mf*16 + l15;
        pb[mf] = *(const bf16x8*)(pbuf + ml*256 + ((s*64 + g*16) ^ ((ml&15)<<4)));
      }
      if (t < 17 && s < 2) computePh(n0 + 128, (t+1)&1, s);
      __builtin_amdgcn_s_setprio(1);
      #pragma unroll
      for (int cf = 0; cf < 4; ++cf)
        #pragma unroll
        for (int mf = 0; mf < 4; ++mf)
          acc[cf][mf] = __builtin_amdgcn_mfma_f32_16x16x32_bf16(av[s&1][cf], pb[mf], acc[cf][mf], 0, 0, 0);
      __builtin_amdgcn_s_setprio(0);
      if (s < 2){
        #pragma unroll
        for (int cf = 0; cf < 4; ++cf)
          av[s][cf] = *(const bf16x8*)(Vb + (size_t)cf*16*N_ + n0 + (s+2)*32 + g*8);
      }
    }
    __syncthreads();
  }
  unsigned short* ap = att + (((size_t)a*8 + b)*256)*N_;
  #pragma unroll
  for (int cf = 0; cf < 4; ++cf)
    #pragma unroll
    for (int mf = 0; mf < 4; ++mf)
      #pragma unroll
      for (int r = 0; r < 4; ++r){
        int c = w*64 + cf*16 + g*4 + r;
        int m = m0 + mf*16 + l15;
        ap[(size_t)c*N_ + m] = f2bf(acc[cf][mf][r]);
      }
}

// ---------------- 6. gate GEMM + fuse + MLP -> wmap ----------------
__global__ __launch_bounds__(256, 2) void k_gatemlp(
                           const unsigned short* att, const unsigned short* wgate,
                           const float* gate_b,
                           const float* w1, const float* g1, const float* b1,
                           const float* w2, const float* g2, const float* b2,
                           float* wmap){
  int orig = blockIdx.x;
  int b = orig & 7, m0 = (orig >> 3)*32;   // XCD pin: att[.][b] stays in XCD(b) L2
  int lane = threadIdx.x & 63, w = threadIdx.x >> 6;
  int l15 = lane & 15, g = lane >> 4;
  __shared__ unsigned short ats[32][520];   // [m local][k = a*256+c]
  __shared__ unsigned short fvs[256][34];   // [c][m local] bf16
  __shared__ float hs[24][33];
  int row8 = threadIdx.x >> 3;      // 0..31
  int mq = (threadIdx.x & 7)*4;     // m offset
  for (int rb = 0; rb < 16; ++rb){
    int k = rb*32 + row8;           // 0..511
    int aa = k >> 8, c = k & 255;
    size_t base = (((size_t)aa*8 + b)*256 + c)*N_ + m0 + mq;
    u16x4 p0 = *(const u16x4*)(att + base);
    #pragma unroll
    for (int j = 0; j < 4; ++j) ats[mq + j][k] = p0[j];
  }
  __syncthreads();
  f32x4 acc[4][2];
  #pragma unroll
  for (int i = 0; i < 4; ++i){ acc[i][0] = 0.f; acc[i][1] = 0.f; }
  for (int k0 = 0; k0 < 512; k0 += 32){
    bf16x8 aw[4], bt[2];
    #pragma unroll
    for (int of = 0; of < 4; ++of)
      aw[of] = *(const bf16x8*)(wgate + (size_t)(w*64 + of*16 + l15)*512 + k0 + g*8);
    #pragma unroll
    for (int mf = 0; mf < 2; ++mf)
      bt[mf] = *(const bf16x8*)(&ats[mf*16 + l15][k0 + g*8]);
    #pragma unroll
    for (int of = 0; of < 4; ++of)
      #pragma unroll
      for (int mf = 0; mf < 2; ++mf)
        acc[of][mf] = __builtin_amdgcn_mfma_f32_16x16x32_bf16(aw[of], bt[mf], acc[of][mf], 0, 0, 0);
  }
  #pragma unroll
  for (int of = 0; of < 4; ++of){
    int o4 = w*64 + of*16 + g*4;
    float4 gb4 = *(const float4*)(gate_b + o4);
    #pragma unroll
    for (int mf = 0; mf < 2; ++mf){
      int ml = mf*16 + l15;
      u16x4 ra4 = *(const u16x4*)(&ats[ml][o4]);
      u16x4 da4 = *(const u16x4*)(&ats[ml][256 + o4]);
      #pragma unroll
      for (int r = 0; r < 4; ++r){
        float gg = sigm(acc[of][mf][r] + (&gb4.x)[r]);
        float ra = bf2f(ra4[r]);
        float da = bf2f(da4[r]);
        float fv = ra*gg + da*(1.f - gg) + ra*da;
        fvs[o4 + r][ml] = f2bf(fv);
      }
    }
  }
  __syncthreads();
  {
    int m = threadIdx.x & 31, jg = threadIdx.x >> 5;   // jg 0..7, 3 j each
    const float* w1r0 = w1 + (size_t)(jg*3+0)*256;
    const float* w1r1 = w1 + (size_t)(jg*3+1)*256;
    const float* w1r2 = w1 + (size_t)(jg*3+2)*256;
    float h0 = 0.f, h1 = 0.f, h2 = 0.f;
    for (int c = 0; c < 256; ++c){
      float v = bf2f(fvs[c][m]);
      h0 += w1r0[c]*v; h1 += w1r1[c]*v; h2 += w1r2[c]*v;
    }
    hs[jg*3+0][m] = h0; hs[jg*3+1][m] = h1; hs[jg*3+2][m] = h2;
  }
  __syncthreads();
  if (threadIdx.x < 32){
    int mm = threadIdx.x;
    float s2 = 0.f;
    #pragma unroll
    for (int j = 0; j < 24; ++j){
      float hj = fmaxf(hs[j][mm]*(BN_SC*g1[j]) + b1[j], 0.f);
      s2 += w2[j]*hj;
    }
    s2 = s2*(BN_SC*g2[0]) + b2[0];
    wmap[b*N_ + m0 + mm] = sigm(sigm(s2));
  }
}

// ---------------- 7. final combine (grid-stride, full occupancy) ----------------
__global__ void k_final(const float* rgb, const float* chm, const float* sa, const float* ca,
                        const float* wmap, float* out){
  const int total4 = B_*C_*N_/4;
  for (int i = blockIdx.x*blockDim.x + threadIdx.x; i < total4; i += gridDim.x*blockDim.x){
    int e = i*4;
    int b = e / (C_*N_);
    int rem = e % (C_*N_);
    int c = rem / N_;
    int pix = rem % N_;
    float4 rv = *(const float4*)(rgb + e);
    float4 cv = *(const float4*)(chm + e);
    float4 sc = *(const float4*)(sa + (size_t)(B_ + b)*N_ + pix);
    float4 sr = *(const float4*)(sa + (size_t)b*N_ + pix);
    float4 wm = *(const float4*)(wmap + (size_t)b*N_ + pix);
    float cac = ca[(B_ + b)*C_ + c];
    float car = ca[b*C_ + c];
    float4 o;
    o.x = rv.x*sc.x*cac + cv.x*sr.x*car*wm.x;
    o.y = rv.y*sc.y*cac + cv.y*sr.y*car*wm.y;
    o.z = rv.z*sc.z*cac + cv.z*sr.z*car*wm.z;
    o.w = rv.w*sc.w*cac + cv.w*sr.w*car*wm.w;
    *(float4*)(out + e) = o;
  }
}

extern "C" void kernel_launch(void* const* d_in, const int* in_sizes, int n_in,
                              void* d_out, int out_size, void* d_ws, size_t ws_size,
                              hipStream_t stream){
  if (ws_size < WS_NEEDED) return;
  const float* rgb      = (const float*)d_in[0];
  const float* chm      = (const float*)d_in[1];
  const float* rgb_sa_w = (const float*)d_in[2];
  const float* rgb_sa_b = (const float*)d_in[3];
  const float* chm_sa_w = (const float*)d_in[4];
  const float* chm_sa_b = (const float*)d_in[5];
  const float* rgb_fc1_w= (const float*)d_in[6];
  const float* rgb_fc1_b= (const float*)d_in[7];
  const float* rgb_fc2_w= (const float*)d_in[8];
  const float* rgb_fc2_b= (const float*)d_in[9];
  const float* chm_fc1_w= (const float*)d_in[10];
  const float* chm_fc1_b= (const float*)d_in[11];
  const float* chm_fc2_w= (const float*)d_in[12];
  const float* chm_fc2_b= (const float*)d_in[13];
  const float* rq_w = (const float*)d_in[14];
  const float* rq_b = (const float*)d_in[15];
  const float* rk_w = (const float*)d_in[16];
  const float* rk_b = (const float*)d_in[17];
  const float* rv_w = (const float*)d_in[18];
  const float* rv_b = (const float*)d_in[19];
  const float* dq_w = (const float*)d_in[20];
  const float* dq_b = (const float*)d_in[21];
  const float* dk_w = (const float*)d_in[22];
  const float* dk_b = (const float*)d_in[23];
  const float* dv_w = (const float*)d_in[24];
  const float* dv_b = (const float*)d_in[25];
  const float* gate_w = (const float*)d_in[26];
  const float* gate_b = (const float*)d_in[27];
  const float* mlp1_w = (const float*)d_in[28];
  const float* mlp1_g = (const float*)d_in[29];
  const float* mlp1_b = (const float*)d_in[30];
  const float* mlp2_w = (const float*)d_in[31];
  const float* mlp2_g = (const float*)d_in[32];
  const float* mlp2_b = (const float*)d_in[33];

  char* ws = (char*)d_ws;
  unsigned short* wsu   = (unsigned short*)d_ws;
  float* sconv = (float*)(ws + OFF_SCONV);
  float* sa    = (float*)(ws + OFF_SA);
  float* ca    = (float*)(ws + OFF_CA);
  float* wmap  = (float*)(ws + OFF_WMAP);
  float* pcs   = (float*)(ws + OFF_PCS);
  float* pcm   = (float*)(ws + OFF_PCM);
  unsigned short* wproj = (unsigned short*)(ws + OFF_WPROJ);
  unsigned short* wgate = (unsigned short*)(ws + OFF_WGATE);
  unsigned short* att   = (unsigned short*)(ws + OFF_ATT);

  k_prep_w<<<dim3(1152), dim3(256), 0, stream>>>(rq_w, rk_w, rv_w, dq_w, dk_w, dv_w, gate_w, wproj, wgate);
  k_stage<<<dim3(288,2), dim3(256), 0, stream>>>(rgb, chm, wproj, rq_b, rk_b, rv_b, dq_b, dk_b, dv_b,
                                                 wsu, sconv, pcs, pcm);
  k_sa_ca<<<dim3(160), dim3(256), 0, stream>>>(sconv, rgb_sa_w, rgb_sa_b, chm_sa_w, chm_sa_b, sa,
                                               pcs, pcm, rgb_fc1_w, rgb_fc1_b, rgb_fc2_w, rgb_fc2_b,
                                               chm_fc1_w, chm_fc1_b, chm_fc2_w, chm_fc2_b, ca);
  k_phase_a<<<dim3(576), dim3(256), 0, stream>>>(wsu);
  k_pv5<<<dim3(576), dim3(256), 0, stream>>>(wsu, att);
  k_gatemlp<<<dim3(576), dim3(256), 0, stream>>>(att, wgate, gate_b,
                                                 mlp1_w, mlp1_g, mlp1_b, mlp2_w, mlp2_g, mlp2_b, wmap);
  k_final<<<dim3(2048), dim3(256), 0, stream>>>(rgb, chm, sa, ca, wmap, (float*)d_out);
}